// Round 4
// baseline (257.324 us; speedup 1.0000x reference)
//
#include <hip/hip_runtime.h>

// Problem constants (B,C,H,W fixed by the reference setup)
#define B_   8
#define C_   10
#define H_   128
#define W_   128
#define HWSZ (H_ * W_)    // 16384
#define CHW  (C_ * HWSZ)  // 163840

#define TS   16           // spatial tile (16x16 outputs per block)
#define HL   18           // halo extent (TS + 2)
#define HSZ  (HL * HL)    // 324 halo pixels
#define NTHREADS 256      // 1 pixel per thread

__device__ __forceinline__ float sigm(float x)  { return 1.0f / (1.0f + __expf(-x)); }
__device__ __forceinline__ float tanh_(float x) { return 1.0f - 2.0f / (__expf(2.0f * x) + 1.0f); }

// Single fully-fused kernel. All weight accesses use compile-time-constant
// indices off uniform base pointers -> scalar K$ loads (s_load_dword), zero
// LDS / zero VALU cost for weight movement, no prep kernel needed.
__global__ __launch_bounds__(NTHREADS) void fused_graph_kernel(
    const float* __restrict__ f_g,
    const float* __restrict__ h0_g,
    const float* __restrict__ h1_g,
    const float* __restrict__ attw_g,
    const float* __restrict__ attb_g,
    const float* __restrict__ relw_g,
    const float* __restrict__ gamma_g,
    const float* __restrict__ beta_g,
    const float* __restrict__ mean_g,
    const float* __restrict__ var_g,
    const float* __restrict__ gw_g,
    const float* __restrict__ gb_g,
    const float* __restrict__ cw_g,
    const float* __restrict__ cb_g,
    float* __restrict__ out_f,
    float* __restrict__ out_att)
{
    // LDS: halo tile only, float4 per (channel, pixel): (f, h0*att, h1*att, att).
    // 10 * 324 * 16 B = 51.84 KB -> 2 blocks/CU (103.7 KB of 160 KB).
    __shared__ float4 sIn[C_][HSZ];

    const int tid = threadIdx.x;
    const int bx = blockIdx.x, by = blockIdx.y, b = blockIdx.z;

    // attention 1x1 weights: uniform -> SGPRs
    float aw[20];
    #pragma unroll
    for (int i = 0; i < 20; i++) aw[i] = attw_g[i];
    const float ab = attb_g[0];

    // ---- input halo staging; compute att per halo pixel once ----
    const int gy0 = by * TS - 1, gx0 = bx * TS - 1;
    for (int p = tid; p < HSZ; p += NTHREADS) {
        const int hy = p / HL, hx = p - hy * HL;
        const int gy = gy0 + hy, gx = gx0 + hx;
        if (gy >= 0 && gy < H_ && gx >= 0 && gx < W_) {
            const int base = b * CHW + gy * W_ + gx;
            float fv[10], h0v[10], h1v[10];
            float acc = ab;
            #pragma unroll
            for (int ci = 0; ci < 10; ci++) {
                fv[ci]  = f_g [base + ci * HWSZ];
                h0v[ci] = h0_g[base + ci * HWSZ];
                h1v[ci] = h1_g[base + ci * HWSZ];
                acc += aw[ci] * h0v[ci] + aw[10 + ci] * h1v[ci];
            }
            const float att = sigm(acc);
            #pragma unroll
            for (int ci = 0; ci < 10; ci++)
                sIn[ci][p] = make_float4(fv[ci], h0v[ci] * att, h1v[ci] * att, att);
        } else {  // zero padding (conv pad=1)
            #pragma unroll
            for (int ci = 0; ci < 10; ci++)
                sIn[ci][p] = make_float4(0.f, 0.f, 0.f, 0.f);
        }
    }
    __syncthreads();

    // ---- 3x3 conv, f-part shared between both relations; 1 pixel/thread ----
    const int ly = tid >> 4, lx = tid & 15;
    const int hc = (ly + 1) * HL + (lx + 1);

    float accf[10], acc0[10], acc1[10];
    #pragma unroll
    for (int c = 0; c < 10; c++) { accf[c] = 0.f; acc0[c] = 0.f; acc1[c] = 0.f; }

    #pragma unroll 1  // keep 9-tap loop rolled (icache); ci/c fully unrolled
    for (int tap = 0; tap < 9; tap++) {
        const int hi = hc + (tap / 3 - 1) * HL + (tap - (tap / 3) * 3 - 1);
        // rel_w layout: [c_out=10][cin=20][9]; base advanced by tap -> all
        // remaining offsets are compile-time immediates -> s_load_dword
        const float* __restrict__ wt = relw_g + tap;
        #pragma unroll
        for (int ci = 0; ci < 10; ci++) {
            const float4 v = sIn[ci][hi];                 // one ds_read_b128
            #pragma unroll
            for (int c = 0; c < 10; c++) {
                accf[c] += wt[(c * 20 + ci)      * 9] * v.x;   // f-part (cin=ci)
                const float wa = wt[(c * 20 + 10 + ci) * 9];   // att-part (cin=10+ci)
                acc0[c] += wa * v.y;
                acc1[c] += wa * v.z;
            }
        }
    }

    // ---- BN (epilogue) + ReLU + sum; ConvGRU (1x1) ----
    float ch[10], fc[10], attv;
    {
        const float4 cv = sIn[0][hc];
        fc[0] = cv.x; attv = cv.w;
    }
    #pragma unroll
    for (int c = 1; c < 10; c++) fc[c] = sIn[c][hc].x;
    #pragma unroll
    for (int c = 0; c < 10; c++) {
        const float sc = gamma_g[c] * rsqrtf(var_g[c] + 1e-5f);
        const float bi = beta_g[c] - mean_g[c] * sc;
        ch[c] = fmaxf((accf[c] + acc0[c]) * sc + bi, 0.f)
              + fmaxf((accf[c] + acc1[c]) * sc + bi, 0.f);
    }

    float g[20];
    #pragma unroll
    for (int o = 0; o < 20; o++) g[o] = gb_g[o];
    #pragma unroll
    for (int i = 0; i < 10; i++) {
        #pragma unroll
        for (int o = 0; o < 20; o++)   // gates_w [o=20][in=20]: in<10 -> comp_h, in>=10 -> f
            g[o] += ch[i] * gw_g[o * 20 + i] + fc[i] * gw_g[o * 20 + 10 + i];
    }
    float cd[10];
    #pragma unroll
    for (int c = 0; c < 10; c++) cd[c] = cb_g[c];
    #pragma unroll
    for (int i = 0; i < 10; i++) {
        const float rf = sigm(g[i]) * fc[i];   // reset * f
        #pragma unroll
        for (int c = 0; c < 10; c++)           // can_w [c=10][in=20]
            cd[c] += ch[i] * cw_g[c * 20 + i] + rf * cw_g[c * 20 + 10 + i];
    }

    const int gy = by * TS + ly, gx = bx * TS + lx;
    #pragma unroll
    for (int c = 0; c < 10; c++) {
        const float u = sigm(g[10 + c]);       // update gate
        out_f[((b * C_ + c) * H_ + gy) * W_ + gx] = (1.f - u) * fc[c] + u * tanh_(cd[c]);
    }
    out_att[(b * H_ + gy) * W_ + gx] = attv;
}

extern "C" void kernel_launch(void* const* d_in, const int* in_sizes, int n_in,
                              void* d_out, int out_size, void* d_ws, size_t ws_size,
                              hipStream_t stream) {
    (void)in_sizes; (void)n_in; (void)d_ws; (void)ws_size; (void)out_size;
    const float* f   = (const float*)d_in[0];
    const float* h0  = (const float*)d_in[1];
    const float* h1  = (const float*)d_in[2];
    // d_in[3] = p_nodes, d_in[4] = xf: unused by the reference -> never read
    const float* aw  = (const float*)d_in[5];
    const float* ab  = (const float*)d_in[6];
    const float* rw  = (const float*)d_in[7];
    const float* gam = (const float*)d_in[8];
    const float* bet = (const float*)d_in[9];
    const float* mea = (const float*)d_in[10];
    const float* var = (const float*)d_in[11];
    const float* gw  = (const float*)d_in[12];
    const float* gb  = (const float*)d_in[13];
    const float* cw  = (const float*)d_in[14];
    const float* cb  = (const float*)d_in[15];

    float* out_f   = (float*)d_out;
    float* out_att = out_f + (B_ * C_ * H_ * W_);

    dim3 grid(W_ / TS, H_ / TS, B_);
    fused_graph_kernel<<<grid, dim3(NTHREADS), 0, stream>>>(
        f, h0, h1, aw, ab, rw, gam, bet, mea, var, gw, gb, cw, cb, out_f, out_att);
}